// Round 2
// baseline (340.526 us; speedup 1.0000x reference)
//
#include <hip/hip_runtime.h>

typedef unsigned short u16;
typedef unsigned int   u32;
typedef __bf16 bf16x8 __attribute__((ext_vector_type(8)));
typedef float  f32x4  __attribute__((ext_vector_type(4)));

__device__ __forceinline__ u16 f2bf(float f) {
  u32 u = __float_as_uint(f);
  u32 r = (u + 0x7fffu + ((u >> 16) & 1u)) >> 16;   // RNE
  return (u16)r;
}

typedef const __attribute__((address_space(1))) u32* gp1;
typedef __attribute__((address_space(3))) u32* lp3;
__device__ __forceinline__ void gload16(const void* g, void* l) {
  __builtin_amdgcn_global_load_lds((gp1)g, (lp3)l, 16, 0, 0);
}

__device__ __forceinline__ f32x4 mfma16(bf16x8 a, bf16x8 b, f32x4 c) {
  return __builtin_amdgcn_mfma_f32_16x16x32_bf16(a, b, c, 0, 0, 0);
}

__device__ __forceinline__ int swz8(int r) { return (r ^ (r >> 3)) & 7; }

// ---------------- cast fp32 -> bf16, 8 elems/thread ----------------
__global__ __launch_bounds__(256) void cast_bf16(const float* __restrict__ s,
                                                 u16* __restrict__ d, int n8) {
  int i = blockIdx.x * 256 + threadIdx.x;
  if (i >= n8) return;
  const float4* s4 = (const float4*)s;
  float4 a = s4[2 * i], b = s4[2 * i + 1];
  uint4 o;
  o.x = (u32)f2bf(a.x) | ((u32)f2bf(a.y) << 16);
  o.y = (u32)f2bf(a.z) | ((u32)f2bf(a.w) << 16);
  o.z = (u32)f2bf(b.x) | ((u32)f2bf(b.y) << 16);
  o.w = (u32)f2bf(b.z) | ((u32)f2bf(b.w) << 16);
  ((uint4*)d)[i] = o;
}

// ---------------- QKV GEMM: C(8192x2304) = Xb(8192x768) * Wqkv^T ----------------
__global__ __launch_bounds__(256) void gemm_qkv(
    const u16* __restrict__ A, const u16* __restrict__ Bm,
    const float* __restrict__ bias,
    u16* __restrict__ Q, u16* __restrict__ K, u16* __restrict__ V) {
  __shared__ u16 As[128 * 32];
  __shared__ u16 Bs[128 * 32];
  const int tid = threadIdx.x, w = tid >> 6, l = tid & 63;
  const int lr = l & 15, lg = l >> 4;
  const int n0 = blockIdx.x * 128, m0 = blockIdx.y * 128;
  const int wr = (w >> 1) * 64, wc = (w & 1) * 64;
  f32x4 acc[4][4] = {};
  for (int kt = 0; kt < 768; kt += 32) {
    __syncthreads();
    const u16* Ab = A + m0 * 768 + kt;
    const u16* Bb = Bm + n0 * 768 + kt;
#pragma unroll
    for (int i = 0; i < 2; ++i) {
      int c = (i * 4 + w) * 64 + l;
      gload16(Ab + (c >> 2) * 768 + (c & 3) * 8, (char*)As + c * 16);
      gload16(Bb + (c >> 2) * 768 + (c & 3) * 8, (char*)Bs + c * 16);
    }
    __syncthreads();
    bf16x8 af[4], bfr[4];
#pragma unroll
    for (int m = 0; m < 4; ++m)
      af[m] = *(const bf16x8*)&As[(wr + m * 16 + lr) * 32 + lg * 8];
#pragma unroll
    for (int n = 0; n < 4; ++n)
      bfr[n] = *(const bf16x8*)&Bs[(wc + n * 16 + lr) * 32 + lg * 8];
#pragma unroll
    for (int m = 0; m < 4; ++m)
#pragma unroll
      for (int n = 0; n < 4; ++n) acc[m][n] = mfma16(af[m], bfr[n], acc[m][n]);
  }
#pragma unroll
  for (int n = 0; n < 4; ++n) {
    int f = n0 + wc + n * 16 + lr;
    float bv = bias[f];
    int three = f / 768;
    int hd = f - three * 768;
    int h = hd >> 6, dd = hd & 63;
    u16* dst = (three == 0) ? Q : (three == 1 ? K : V);
    float sc = (three == 0) ? 0.125f : 1.0f;
#pragma unroll
    for (int m = 0; m < 4; ++m) {
      int row0 = m0 + wr + m * 16 + lg * 4;
#pragma unroll
      for (int j = 0; j < 4; ++j) {
        int row = row0 + j;
        int b = row >> 11, ns = row & 2047;
        float val = (acc[m][n][j] + bv) * sc;
        dst[(((b * 12 + h) * 2048 + ns) << 6) + dd] = f2bf(val);
      }
    }
  }
}

// ---------------- flash attention, 128 q-rows/block, kv tiles of 64, swizzled LDS ----------------
__global__ __launch_bounds__(256, 3) void attn_kernel(
    const u16* __restrict__ Q, const u16* __restrict__ K,
    const u16* __restrict__ V, u16* __restrict__ O) {
  __shared__ u16 Ks[64 * 64];    // [kv][d], chunk-swizzled
  __shared__ u16 Vt[64 * 64];    // [d][kv], chunk-swizzled
  __shared__ u16 Ps[128 * 64];   // [q][kv], chunk-swizzled
  const int tid = threadIdx.x, w = tid >> 6, l = tid & 63;
  const int lr = l & 15, lg = l >> 4;
  int bi = blockIdx.x;
  int qt = bi & 15, h = (bi >> 4) % 12, b = bi / 192;
  const u16* Qp = Q + ((size_t)(b * 12 + h) * 2048 + qt * 128) * 64;
  const u16* Kp = K + (size_t)(b * 12 + h) * 2048 * 64;
  const u16* Vp = V + (size_t)(b * 12 + h) * 2048 * 64;
  u16* Op = O + (size_t)(b * 2048 + qt * 128) * 768 + h * 64;

  // Q fragments: straight from global into registers (contiguous 16B per lane)
  bf16x8 aq[2][2];
#pragma unroll
  for (int m = 0; m < 2; ++m)
#pragma unroll
    for (int ks = 0; ks < 2; ++ks)
      aq[m][ks] = *(const bf16x8*)&Qp[(w * 32 + m * 16 + lr) * 64 + ks * 32 + lg * 8];

  f32x4 aO[2][4] = {};
  f32x4 Mx[2], Ls[2];
#pragma unroll
  for (int mt = 0; mt < 2; ++mt)
#pragma unroll
    for (int j = 0; j < 4; ++j) { Mx[mt][j] = -1e30f; Ls[mt][j] = 0.0f; }

  for (int kt = 0; kt < 32; ++kt) {
    const u16* Kt = Kp + kt * 4096;
    const u16* Vg = Vp + kt * 4096;
    // V tile into regs BEFORE barrier: overlaps previous tile's PV compute
    uint4 dv0 = *(const uint4*)(Vg + (0 * 256 + tid) * 8);
    uint4 dv1 = *(const uint4*)(Vg + (1 * 256 + tid) * 8);
    __syncthreads();                            // prev tile done with Ks/Vt/Ps
    // K: global_load_lds, swizzle applied on SOURCE address (LDS dest linear)
#pragma unroll
    for (int i = 0; i < 2; ++i) {
      int c = i * 256 + tid;
      int row = c >> 3, cc = c & 7;
      gload16(Kt + row * 64 + ((cc ^ swz8(row)) << 3), (char*)Ks + c * 16);
    }
    // V transposed via regs, swizzled scalar writes (2-way banks)
#pragma unroll
    for (int i = 0; i < 2; ++i) {
      int c = i * 256 + tid;
      int n = c >> 3, d0 = (c & 7) * 8;
      uint4 dv = i ? dv1 : dv0;
      u32 px;
#define VT_W(dd, val) *(u16*)((char*)Vt + (dd) * 128 + ((((n) >> 3) ^ swz8(dd)) << 4) + ((n) & 7) * 2) = (u16)(val)
      px = dv.x; VT_W(d0 + 0, px); VT_W(d0 + 1, px >> 16);
      px = dv.y; VT_W(d0 + 2, px); VT_W(d0 + 3, px >> 16);
      px = dv.z; VT_W(d0 + 4, px); VT_W(d0 + 5, px >> 16);
      px = dv.w; VT_W(d0 + 6, px); VT_W(d0 + 7, px >> 16);
#undef VT_W
    }
    __syncthreads();                            // staging complete

    // S = Q*K^T  (wave: 32 q-rows x 64 kv-cols)
    f32x4 S[2][4] = {};
#pragma unroll
    for (int ks = 0; ks < 2; ++ks)
#pragma unroll
      for (int nt = 0; nt < 4; ++nt) {
        int row = nt * 16 + lr;
        bf16x8 bk = *(const bf16x8*)((char*)Ks + row * 128 +
                                     (((ks * 4 + lg) ^ swz8(row)) << 4));
        S[0][nt] = mfma16(aq[0][ks], bk, S[0][nt]);
        S[1][nt] = mfma16(aq[1][ks], bk, S[1][nt]);
      }

    // online softmax (rows in 16-lane groups)
#pragma unroll
    for (int mt = 0; mt < 2; ++mt) {
      f32x4 tmax = S[mt][0];
#pragma unroll
      for (int nt = 1; nt < 4; ++nt)
#pragma unroll
        for (int j = 0; j < 4; ++j) tmax[j] = fmaxf(tmax[j], S[mt][nt][j]);
#pragma unroll
      for (int msk = 1; msk < 16; msk <<= 1)
#pragma unroll
        for (int j = 0; j < 4; ++j)
          tmax[j] = fmaxf(tmax[j], __shfl_xor(tmax[j], msk, 16));
      f32x4 mnew, sc;
#pragma unroll
      for (int j = 0; j < 4; ++j) {
        mnew[j] = fmaxf(Mx[mt][j], tmax[j]);
        sc[j] = __expf(Mx[mt][j] - mnew[j]);
      }
      f32x4 rsum = {};
#pragma unroll
      for (int nt = 0; nt < 4; ++nt) {
        int col = nt * 16 + lr;
#pragma unroll
        for (int j = 0; j < 4; ++j) {
          float p = __expf(S[mt][nt][j] - mnew[j]);
          rsum[j] += p;
          int row = w * 32 + mt * 16 + lg * 4 + j;
          *(u16*)((char*)Ps + row * 128 + ((((col >> 3)) ^ swz8(row)) << 4) +
                  (col & 7) * 2) = f2bf(p);
        }
      }
#pragma unroll
      for (int msk = 1; msk < 16; msk <<= 1)
#pragma unroll
        for (int j = 0; j < 4; ++j) rsum[j] += __shfl_xor(rsum[j], msk, 16);
#pragma unroll
      for (int j = 0; j < 4; ++j) {
        Ls[mt][j] = Ls[mt][j] * sc[j] + rsum[j];
        Mx[mt][j] = mnew[j];
      }
#pragma unroll
      for (int dt = 0; dt < 4; ++dt) aO[mt][dt] *= sc;
    }
    __syncthreads();                            // Ps visible

    // O += P*V
#pragma unroll
    for (int ks = 0; ks < 2; ++ks) {
      bf16x8 ap[2];
#pragma unroll
      for (int mt = 0; mt < 2; ++mt) {
        int row = w * 32 + mt * 16 + lr;
        ap[mt] = *(const bf16x8*)((char*)Ps + row * 128 +
                                  (((ks * 4 + lg) ^ swz8(row)) << 4));
      }
#pragma unroll
      for (int dt = 0; dt < 4; ++dt) {
        int row = dt * 16 + lr;
        bf16x8 bv = *(const bf16x8*)((char*)Vt + row * 128 +
                                     (((ks * 4 + lg) ^ swz8(row)) << 4));
        aO[0][dt] = mfma16(ap[0], bv, aO[0][dt]);
        aO[1][dt] = mfma16(ap[1], bv, aO[1][dt]);
      }
    }
  }

#pragma unroll
  for (int mt = 0; mt < 2; ++mt)
#pragma unroll
    for (int dt = 0; dt < 4; ++dt)
#pragma unroll
      for (int j = 0; j < 4; ++j) {
        int row = w * 32 + mt * 16 + lg * 4 + j;
        float val = aO[mt][dt][j] / Ls[mt][j];
        Op[(size_t)row * 768 + dt * 16 + lr] = f2bf(val);
      }
}

// ---------------- out GEMM: C(8192x768) = Ob(8192x768) * Wout^T + b, fp32 out ----------------
__global__ __launch_bounds__(256) void gemm_out(
    const u16* __restrict__ A, const u16* __restrict__ Bm,
    const float* __restrict__ bias, float* __restrict__ C) {
  __shared__ u16 As[128 * 32];
  __shared__ u16 Bs[128 * 32];
  const int tid = threadIdx.x, w = tid >> 6, l = tid & 63;
  const int lr = l & 15, lg = l >> 4;
  const int n0 = blockIdx.x * 128, m0 = blockIdx.y * 128;
  const int wr = (w >> 1) * 64, wc = (w & 1) * 64;
  f32x4 acc[4][4] = {};
  for (int kt = 0; kt < 768; kt += 32) {
    __syncthreads();
    const u16* Ab = A + m0 * 768 + kt;
    const u16* Bb = Bm + n0 * 768 + kt;
#pragma unroll
    for (int i = 0; i < 2; ++i) {
      int c = (i * 4 + w) * 64 + l;
      gload16(Ab + (c >> 2) * 768 + (c & 3) * 8, (char*)As + c * 16);
      gload16(Bb + (c >> 2) * 768 + (c & 3) * 8, (char*)Bs + c * 16);
    }
    __syncthreads();
    bf16x8 af[4], bfr[4];
#pragma unroll
    for (int m = 0; m < 4; ++m)
      af[m] = *(const bf16x8*)&As[(wr + m * 16 + lr) * 32 + lg * 8];
#pragma unroll
    for (int n = 0; n < 4; ++n)
      bfr[n] = *(const bf16x8*)&Bs[(wc + n * 16 + lr) * 32 + lg * 8];
#pragma unroll
    for (int m = 0; m < 4; ++m)
#pragma unroll
      for (int n = 0; n < 4; ++n) acc[m][n] = mfma16(af[m], bfr[n], acc[m][n]);
  }
#pragma unroll
  for (int n = 0; n < 4; ++n) {
    int f = n0 + wc + n * 16 + lr;
    float bv = bias[f];
#pragma unroll
    for (int m = 0; m < 4; ++m) {
      int row0 = m0 + wr + m * 16 + lg * 4;
#pragma unroll
      for (int j = 0; j < 4; ++j) {
        int row = row0 + j;
        C[(size_t)row * 768 + f] = acc[m][n][j] + bv;
      }
    }
  }
}

extern "C" void kernel_launch(void* const* d_in, const int* in_sizes, int n_in,
                              void* d_out, int out_size, void* d_ws, size_t ws_size,
                              hipStream_t stream) {
  const float* x     = (const float*)d_in[0];
  const float* w_qkv = (const float*)d_in[1];
  const float* b_qkv = (const float*)d_in[2];
  const float* w_out = (const float*)d_in[3];
  const float* b_out = (const float*)d_in[4];

  char* ws = (char*)d_ws;
  u16* xb    = (u16*)(ws + 0);
  u16* wqkvb = (u16*)(ws + 12582912);
  u16* wob   = (u16*)(ws + 16121856);
  u16* qb    = (u16*)(ws + 17301504);
  u16* kb    = (u16*)(ws + 29884416);
  u16* vb    = (u16*)(ws + 42467328);
  u16* ob    = (u16*)(ws + 55050240);

  cast_bf16<<<786432 / 256, 256, 0, stream>>>(x, xb, 786432);
  cast_bf16<<<221184 / 256, 256, 0, stream>>>(w_qkv, wqkvb, 221184);
  cast_bf16<<<73728 / 256, 256, 0, stream>>>(w_out, wob, 73728);

  gemm_qkv<<<dim3(18, 64), 256, 0, stream>>>(xb, wqkvb, b_qkv, qb, kb, vb);
  attn_kernel<<<768, 256, 0, stream>>>(qb, kb, vb, ob);
  gemm_out<<<dim3(6, 64), 256, 0, stream>>>(ob, wob, b_out, (float*)d_out);
}

// Round 3
// 265.757 us; speedup vs baseline: 1.2813x; 1.2813x over previous
//
#include <hip/hip_runtime.h>

typedef unsigned short u16;
typedef unsigned int   u32;
typedef __bf16 bf16x8 __attribute__((ext_vector_type(8)));
typedef float  f32x4  __attribute__((ext_vector_type(4)));

__device__ __forceinline__ u16 f2bf(float f) {
  u32 u = __float_as_uint(f);
  u32 r = (u + 0x7fffu + ((u >> 16) & 1u)) >> 16;   // RNE
  return (u16)r;
}

typedef const __attribute__((address_space(1))) u32* gp1;
typedef __attribute__((address_space(3))) u32* lp3;
__device__ __forceinline__ void gload16(const void* g, void* l) {
  __builtin_amdgcn_global_load_lds((gp1)g, (lp3)l, 16, 0, 0);
}

__device__ __forceinline__ f32x4 mfma16(bf16x8 a, bf16x8 b, f32x4 c) {
  return __builtin_amdgcn_mfma_f32_16x16x32_bf16(a, b, c, 0, 0, 0);
}

__device__ __forceinline__ int swz8(int r) { return (r ^ (r >> 3)) & 7; }

// ---------------- cast fp32 -> bf16, 8 elems/thread ----------------
__global__ __launch_bounds__(256) void cast_bf16(const float* __restrict__ s,
                                                 u16* __restrict__ d, int n8) {
  int i = blockIdx.x * 256 + threadIdx.x;
  if (i >= n8) return;
  const float4* s4 = (const float4*)s;
  float4 a = s4[2 * i], b = s4[2 * i + 1];
  uint4 o;
  o.x = (u32)f2bf(a.x) | ((u32)f2bf(a.y) << 16);
  o.y = (u32)f2bf(a.z) | ((u32)f2bf(a.w) << 16);
  o.z = (u32)f2bf(b.x) | ((u32)f2bf(b.y) << 16);
  o.w = (u32)f2bf(b.z) | ((u32)f2bf(b.w) << 16);
  ((uint4*)d)[i] = o;
}

// ---------------- QKV GEMM: C(8192x2304) = Xb(8192x768) * Wqkv^T ----------------
__global__ __launch_bounds__(256) void gemm_qkv(
    const u16* __restrict__ A, const u16* __restrict__ Bm,
    const float* __restrict__ bias,
    u16* __restrict__ Q, u16* __restrict__ K, u16* __restrict__ V) {
  __shared__ u16 As[128 * 32];
  __shared__ u16 Bs[128 * 32];
  const int tid = threadIdx.x, w = tid >> 6, l = tid & 63;
  const int lr = l & 15, lg = l >> 4;
  const int n0 = blockIdx.x * 128, m0 = blockIdx.y * 128;
  const int wr = (w >> 1) * 64, wc = (w & 1) * 64;
  f32x4 acc[4][4] = {};
  for (int kt = 0; kt < 768; kt += 32) {
    __syncthreads();
    const u16* Ab = A + m0 * 768 + kt;
    const u16* Bb = Bm + n0 * 768 + kt;
#pragma unroll
    for (int i = 0; i < 2; ++i) {
      int c = (i * 4 + w) * 64 + l;
      gload16(Ab + (c >> 2) * 768 + (c & 3) * 8, (char*)As + c * 16);
      gload16(Bb + (c >> 2) * 768 + (c & 3) * 8, (char*)Bs + c * 16);
    }
    __syncthreads();
    bf16x8 af[4], bfr[4];
#pragma unroll
    for (int m = 0; m < 4; ++m)
      af[m] = *(const bf16x8*)&As[(wr + m * 16 + lr) * 32 + lg * 8];
#pragma unroll
    for (int n = 0; n < 4; ++n)
      bfr[n] = *(const bf16x8*)&Bs[(wc + n * 16 + lr) * 32 + lg * 8];
#pragma unroll
    for (int m = 0; m < 4; ++m)
#pragma unroll
      for (int n = 0; n < 4; ++n) acc[m][n] = mfma16(af[m], bfr[n], acc[m][n]);
  }
#pragma unroll
  for (int n = 0; n < 4; ++n) {
    int f = n0 + wc + n * 16 + lr;
    float bv = bias[f];
    int three = f / 768;
    int hd = f - three * 768;
    int h = hd >> 6, dd = hd & 63;
    u16* dst = (three == 0) ? Q : (three == 1 ? K : V);
    float sc = (three == 0) ? 0.125f : 1.0f;
#pragma unroll
    for (int m = 0; m < 4; ++m) {
      int row0 = m0 + wr + m * 16 + lg * 4;
#pragma unroll
      for (int j = 0; j < 4; ++j) {
        int row = row0 + j;
        int b = row >> 11, ns = row & 2047;
        float val = (acc[m][n][j] + bv) * sc;
        dst[(((b * 12 + h) * 2048 + ns) << 6) + dd] = f2bf(val);
      }
    }
  }
}

// ---------------- flash attention: 128 q-rows/block, kv tiles of 64 ----------------
// 2-phase pipeline (double-buffered K/Vt, 1 barrier/iter), XCD-swizzled blocks
__device__ __forceinline__ void vt_store(u16* vtb, int tid, uint4 dva, uint4 dvb) {
#define VT_W(dd, n, val)                                                      \
  *(u16*)((char*)vtb + (dd) * 128 + ((((n) >> 3) ^ swz8(dd)) << 4) +          \
          ((n) & 7) * 2) = (u16)(val)
#pragma unroll
  for (int i = 0; i < 2; ++i) {
    int c = i * 256 + tid;
    int n = c >> 3, d0 = (c & 7) * 8;
    uint4 dv = i ? dvb : dva;
    u32 px;
    px = dv.x; VT_W(d0 + 0, n, px); VT_W(d0 + 1, n, px >> 16);
    px = dv.y; VT_W(d0 + 2, n, px); VT_W(d0 + 3, n, px >> 16);
    px = dv.z; VT_W(d0 + 4, n, px); VT_W(d0 + 5, n, px >> 16);
    px = dv.w; VT_W(d0 + 6, n, px); VT_W(d0 + 7, n, px >> 16);
  }
#undef VT_W
}

__global__ __launch_bounds__(256, 3) void attn_kernel(
    const u16* __restrict__ Q, const u16* __restrict__ K,
    const u16* __restrict__ V, u16* __restrict__ O) {
  __shared__ u16 Ks[2][64 * 64];   // [kv][d], chunk-swizzled, double-buffered
  __shared__ u16 Vt[2][64 * 64];   // [d][kv], chunk-swizzled, double-buffered
  __shared__ u16 Ps[128 * 64];     // [q][kv], wave-private rows (no barrier)
  const int tid = threadIdx.x, w = tid >> 6, l = tid & 63;
  const int lr = l & 15, lg = l >> 4;
  // XCD swizzle: consecutive dispatch ids go to XCDs round-robin; make each
  // XCD own 6 whole heads (16 q-blocks each) so K/V streams L2-hit.
  int d0i = blockIdx.x;
  int bi = (d0i & 7) * 96 + (d0i >> 3);
  int qt = bi & 15, h = (bi >> 4) % 12, b = bi / 192;
  const u16* Qp = Q + ((size_t)(b * 12 + h) * 2048 + qt * 128) * 64;
  const u16* Kp = K + (size_t)(b * 12 + h) * 2048 * 64;
  const u16* Vp = V + (size_t)(b * 12 + h) * 2048 * 64;
  u16* Op = O + (size_t)(b * 2048 + qt * 128) * 768 + h * 64;

  // Q fragments straight from global into registers
  bf16x8 aq[2][2];
#pragma unroll
  for (int m = 0; m < 2; ++m)
#pragma unroll
    for (int ks = 0; ks < 2; ++ks)
      aq[m][ks] = *(const bf16x8*)&Qp[(w * 32 + m * 16 + lr) * 64 + ks * 32 + lg * 8];

  // prologue: stage tile 0
#pragma unroll
  for (int i = 0; i < 2; ++i) {
    int c = i * 256 + tid;
    int row = c >> 3, cc = c & 7;
    gload16(Kp + row * 64 + ((cc ^ swz8(row)) << 3), (char*)Ks[0] + c * 16);
  }
  {
    uint4 a0 = *(const uint4*)(Vp + tid * 8);
    uint4 a1 = *(const uint4*)(Vp + (256 + tid) * 8);
    vt_store(Vt[0], tid, a0, a1);
  }
  __syncthreads();

  f32x4 aO[2][4] = {};
  f32x4 Mx[2], Ls[2];
#pragma unroll
  for (int mt = 0; mt < 2; ++mt)
#pragma unroll
    for (int j = 0; j < 4; ++j) { Mx[mt][j] = -1e30f; Ls[mt][j] = 0.0f; }

  for (int kt = 0; kt < 32; ++kt) {
    const int p = kt & 1;
    const int ktn = (kt < 31) ? kt + 1 : 31;       // clamp (extra load harmless)
    const u16* Kn = Kp + ktn * 4096;
    const u16* Vn = Vp + ktn * 4096;

    // ---- prefetch next tile: K -> Ks[p^1] (async), V -> regs ----
#pragma unroll
    for (int i = 0; i < 2; ++i) {
      int c = i * 256 + tid;
      int row = c >> 3, cc = c & 7;
      gload16(Kn + row * 64 + ((cc ^ swz8(row)) << 3), (char*)Ks[p ^ 1] + c * 16);
    }
    uint4 dva = *(const uint4*)(Vn + tid * 8);
    uint4 dvb = *(const uint4*)(Vn + (256 + tid) * 8);

    // ---- S = Q*K^T from Ks[p] (wave: 32 q-rows x 64 kv-cols) ----
    f32x4 S[2][4] = {};
#pragma unroll
    for (int ks = 0; ks < 2; ++ks)
#pragma unroll
      for (int nt = 0; nt < 4; ++nt) {
        int row = nt * 16 + lr;
        bf16x8 bk = *(const bf16x8*)((char*)Ks[p] + row * 128 +
                                     (((ks * 4 + lg) ^ swz8(row)) << 4));
        S[0][nt] = mfma16(aq[0][ks], bk, S[0][nt]);
        S[1][nt] = mfma16(aq[1][ks], bk, S[1][nt]);
      }

    // ---- online softmax (rows live in 16-lane groups) ----
#pragma unroll
    for (int mt = 0; mt < 2; ++mt) {
      f32x4 tmax = S[mt][0];
#pragma unroll
      for (int nt = 1; nt < 4; ++nt)
#pragma unroll
        for (int j = 0; j < 4; ++j) tmax[j] = fmaxf(tmax[j], S[mt][nt][j]);
#pragma unroll
      for (int msk = 1; msk < 16; msk <<= 1)
#pragma unroll
        for (int j = 0; j < 4; ++j)
          tmax[j] = fmaxf(tmax[j], __shfl_xor(tmax[j], msk, 16));
      f32x4 mnew, sc;
#pragma unroll
      for (int j = 0; j < 4; ++j) {
        mnew[j] = fmaxf(Mx[mt][j], tmax[j]);
        sc[j] = __expf(Mx[mt][j] - mnew[j]);
      }
      f32x4 rsum = {};
#pragma unroll
      for (int nt = 0; nt < 4; ++nt) {
        int col = nt * 16 + lr;
#pragma unroll
        for (int j = 0; j < 4; ++j) {
          float pp = __expf(S[mt][nt][j] - mnew[j]);
          rsum[j] += pp;
          int row = w * 32 + mt * 16 + lg * 4 + j;
          *(u16*)((char*)Ps + row * 128 + ((((col >> 3)) ^ swz8(row)) << 4) +
                  (col & 7) * 2) = f2bf(pp);
        }
      }
#pragma unroll
      for (int msk = 1; msk < 16; msk <<= 1)
#pragma unroll
        for (int j = 0; j < 4; ++j) rsum[j] += __shfl_xor(rsum[j], msk, 16);
#pragma unroll
      for (int j = 0; j < 4; ++j) {
        Ls[mt][j] = Ls[mt][j] * sc[j] + rsum[j];
        Mx[mt][j] = mnew[j];
      }
#pragma unroll
      for (int dt = 0; dt < 4; ++dt) aO[mt][dt] *= sc;
    }

    // ---- write V(t+1) into Vt[p^1] (write-late: latency hidden under QK^T) ----
    vt_store(Vt[p ^ 1], tid, dva, dvb);

    // ---- O += P*V from Ps (wave-private) and Vt[p] ----
#pragma unroll
    for (int ks = 0; ks < 2; ++ks) {
      bf16x8 ap[2];
#pragma unroll
      for (int mt = 0; mt < 2; ++mt) {
        int row = w * 32 + mt * 16 + lr;
        ap[mt] = *(const bf16x8*)((char*)Ps + row * 128 +
                                  (((ks * 4 + lg) ^ swz8(row)) << 4));
      }
#pragma unroll
      for (int dt = 0; dt < 4; ++dt) {
        int row = dt * 16 + lr;
        bf16x8 bv = *(const bf16x8*)((char*)Vt[p] + row * 128 +
                                     (((ks * 4 + lg) ^ swz8(row)) << 4));
        aO[0][dt] = mfma16(ap[0], bv, aO[0][dt]);
        aO[1][dt] = mfma16(ap[1], bv, aO[1][dt]);
      }
    }

    __syncthreads();   // drains K prefetch, orders Vt[p^1] for next iter
  }

#pragma unroll
  for (int mt = 0; mt < 2; ++mt)
#pragma unroll
    for (int dt = 0; dt < 4; ++dt)
#pragma unroll
      for (int j = 0; j < 4; ++j) {
        int row = w * 32 + mt * 16 + lg * 4 + j;
        float val = aO[mt][dt][j] / Ls[mt][j];
        Op[(size_t)row * 768 + dt * 16 + lr] = f2bf(val);
      }
}

// ---------------- out GEMM: C(8192x768) = Ob(8192x768) * Wout^T + b, fp32 out ----------------
__global__ __launch_bounds__(256) void gemm_out(
    const u16* __restrict__ A, const u16* __restrict__ Bm,
    const float* __restrict__ bias, float* __restrict__ C) {
  __shared__ u16 As[128 * 32];
  __shared__ u16 Bs[128 * 32];
  const int tid = threadIdx.x, w = tid >> 6, l = tid & 63;
  const int lr = l & 15, lg = l >> 4;
  const int n0 = blockIdx.x * 128, m0 = blockIdx.y * 128;
  const int wr = (w >> 1) * 64, wc = (w & 1) * 64;
  f32x4 acc[4][4] = {};
  for (int kt = 0; kt < 768; kt += 32) {
    __syncthreads();
    const u16* Ab = A + m0 * 768 + kt;
    const u16* Bb = Bm + n0 * 768 + kt;
#pragma unroll
    for (int i = 0; i < 2; ++i) {
      int c = (i * 4 + w) * 64 + l;
      gload16(Ab + (c >> 2) * 768 + (c & 3) * 8, (char*)As + c * 16);
      gload16(Bb + (c >> 2) * 768 + (c & 3) * 8, (char*)Bs + c * 16);
    }
    __syncthreads();
    bf16x8 af[4], bfr[4];
#pragma unroll
    for (int m = 0; m < 4; ++m)
      af[m] = *(const bf16x8*)&As[(wr + m * 16 + lr) * 32 + lg * 8];
#pragma unroll
    for (int n = 0; n < 4; ++n)
      bfr[n] = *(const bf16x8*)&Bs[(wc + n * 16 + lr) * 32 + lg * 8];
#pragma unroll
    for (int m = 0; m < 4; ++m)
#pragma unroll
      for (int n = 0; n < 4; ++n) acc[m][n] = mfma16(af[m], bfr[n], acc[m][n]);
  }
#pragma unroll
  for (int n = 0; n < 4; ++n) {
    int f = n0 + wc + n * 16 + lr;
    float bv = bias[f];
#pragma unroll
    for (int m = 0; m < 4; ++m) {
      int row0 = m0 + wr + m * 16 + lg * 4;
#pragma unroll
      for (int j = 0; j < 4; ++j) {
        int row = row0 + j;
        C[(size_t)row * 768 + f] = acc[m][n][j] + bv;
      }
    }
  }
}

extern "C" void kernel_launch(void* const* d_in, const int* in_sizes, int n_in,
                              void* d_out, int out_size, void* d_ws, size_t ws_size,
                              hipStream_t stream) {
  const float* x     = (const float*)d_in[0];
  const float* w_qkv = (const float*)d_in[1];
  const float* b_qkv = (const float*)d_in[2];
  const float* w_out = (const float*)d_in[3];
  const float* b_out = (const float*)d_in[4];

  char* ws = (char*)d_ws;
  u16* xb    = (u16*)(ws + 0);
  u16* wqkvb = (u16*)(ws + 12582912);
  u16* wob   = (u16*)(ws + 16121856);
  u16* qb    = (u16*)(ws + 17301504);
  u16* kb    = (u16*)(ws + 29884416);
  u16* vb    = (u16*)(ws + 42467328);
  u16* ob    = (u16*)(ws + 55050240);

  cast_bf16<<<786432 / 256, 256, 0, stream>>>(x, xb, 786432);
  cast_bf16<<<221184 / 256, 256, 0, stream>>>(w_qkv, wqkvb, 221184);
  cast_bf16<<<73728 / 256, 256, 0, stream>>>(w_out, wob, 73728);

  gemm_qkv<<<dim3(18, 64), 256, 0, stream>>>(xb, wqkvb, b_qkv, qb, kb, vb);
  attn_kernel<<<768, 256, 0, stream>>>(qb, kb, vb, ob);
  gemm_out<<<dim3(6, 64), 256, 0, stream>>>(ob, wob, b_out, (float*)d_out);
}